// Round 9
// baseline (55.451 us; speedup 1.0000x reference)
//
#include <hip/hip_runtime.h>
#include <math.h>

// Problem constants (from reference setup_inputs)
constexpr int B_ = 8, N_ = 32768, CAT_ = 128, FEAT_ = 128, K_ = 64;
constexpr float DELTA_ = 0.5f;

typedef __bf16 bf16x8 __attribute__((ext_vector_type(8)));
typedef float f32x4 __attribute__((ext_vector_type(4)));
typedef float f32x16 __attribute__((ext_vector_type(16)));

constexpr int BLOCK = 512;                       // 8 waves
constexpr int NPB   = 256;                       // n-rows per block (32 per wave)
constexpr int GEMM_BLOCKS = (B_ * N_) / NPB;     // 1024

#define AS1 __attribute__((address_space(1)))
#define AS3 __attribute__((address_space(3)))

// ---------------------------------------------------------------------------
// prep: builds bf16 W^T [FEAT][CAT], XOR-swizzled within each row
// (wT_swz[f][c ^ ((f&7)<<3)] = w[c][f]) so a LINEAR global_load_lds copy
// yields a swizzled LDS image (G21). Also produces new_weight.
// grid = CAT_ blocks x FEAT_ threads.
// ---------------------------------------------------------------------------
__global__ void prep_kernel(const float* __restrict__ weight,
                            const int* __restrict__ keys,
                            const float* __restrict__ values,
                            float* __restrict__ outw,    // [CAT][FEAT]
                            __bf16* __restrict__ wTs)    // [FEAT][CAT] swizzled
{
    const int r = blockIdx.x;    // weight row (CAT index = c)
    const int t = threadIdx.x;   // FEAT index (f)
    float w = weight[r * FEAT_ + t];
    wTs[t * CAT_ + (r ^ ((t & 7) << 3))] = (__bf16)w;

    bool keyed = false;
    for (int i = 0; i < K_; ++i) keyed |= (keys[i] == r);
    if (!keyed) outw[r * FEAT_ + t] = w;

    if (r < K_ && t < 64) {
        const int key = keys[r];
        float a0 = DELTA_ * weight[key * FEAT_ + t]      + (1.0f - DELTA_) * values[r * FEAT_ + t];
        float a1 = DELTA_ * weight[key * FEAT_ + t + 64] + (1.0f - DELTA_) * values[r * FEAT_ + t + 64];
        float ss = a0 * a0 + a1 * a1;
        #pragma unroll
        for (int off = 32; off > 0; off >>= 1)
            ss += __shfl_down(ss, off, 64);
        float nrm = sqrtf(__shfl(ss, 0, 64));
        outw[key * FEAT_ + t]      = nrm;
        outw[key * FEAT_ + t + 64] = nrm;
    }
}

// ---------------------------------------------------------------------------
// gemm (32x32x16 MFMA, double-buffered input slabs in LDS):
//   out[b][f][n] = sum_c input[b][n][c] * w[c][f]
//  - INPUT staged via global_load_lds (fire-and-forget, zero VGPR cost ->
//    a full 16KB slab in flight per block; breaks the ~3-loads/wave VGPR
//    throttle that capped R1-R8 at ~4 TB/s effective)
//  - slab layout [c4][256 r][4 floats]: frag ds_read_b128 at stride 16B ->
//    max 4-way bank conflict
//  - one __syncthreads per iter IS the pipeline handshake (drains
//    vmcnt/lgkm; buffer overwritten at iter k was last read at k-1)
//  - weight path + swizzle + 32x32 D-layout epilogue identical to R8
// ---------------------------------------------------------------------------
__global__ __launch_bounds__(BLOCK, 2) void gemm_kernel(
    const float* __restrict__ input,   // [B][N][CAT]
    const __bf16* __restrict__ wTs,    // [FEAT][CAT] bf16, swizzled
    float* __restrict__ out)           // [B][FEAT][N]
{
    __shared__ __bf16 wt[FEAT_ * CAT_];   // 32 KB weight (pre-swizzled image)
    __shared__ float  islab[2 * 4096];    // 2 x 16 KB input slabs

    const int tid  = threadIdx.x;
    const int wid  = tid >> 6;            // 0..7
    const int lane = tid & 63;

    const int bid = blockIdx.x;
    const int b   = bid >> 7;             // 128 blocks per batch
    const int nb  = bid & 127;
    const int nbase = nb * NPB;
    const size_t rowbase = (size_t)b * N_ + nbase;

    // ---- weight staging: 4 x (64 lanes x 16B) per wave = 32 KB total ----
    #pragma unroll
    for (int j = 0; j < 4; ++j) {
        int off = j * 8192 + wid * 1024;  // bytes; wave-uniform LDS base
        __builtin_amdgcn_global_load_lds(
            (const AS1 void*)((const char*)wTs + off + lane * 16),
            (AS3 void*)((char*)wt + off), 16, 0, 0);
    }

    // ---- input slab staging: slab s covers columns s*16..s*16+15 ----
    // LDS float layout: [c4 = col-chunk of 4][r = 0..255][4 floats]
    // thread covers 2 x 16B chunks; dest passed wave-uniform (HW adds lane*16)
    #define STAGE_SLAB(s, dbuf)                                               \
        {                                                                     \
            _Pragma("unroll")                                                 \
            for (int i = 0; i < 2; ++i) {                                     \
                const int L  = i * 8192 + tid * 16;                           \
                const int c4 = L >> 12;                                       \
                const int r  = (L >> 4) & 255;                                \
                const float* src = input + (rowbase + r) * CAT_ + (s) * 16 + c4 * 4; \
                __builtin_amdgcn_global_load_lds(                             \
                    (const AS1 void*)src,                                     \
                    (AS3 void*)((char*)islab + (dbuf) * 16384 + i * 8192 + wid * 1024), \
                    16, 0, 0);                                                \
            }                                                                 \
        }

    STAGE_SLAB(0, 0);

    const int nl = lane & 31;    // n within wave tile / f within mt tile
    const int kg = lane >> 5;    // 0..1, k-group of 8
    const int rloc = wid * 32 + nl;

    f32x16 acc[4];
    #pragma unroll
    for (int i = 0; i < 4; ++i)
        acc[i] = (f32x16)0.0f;

    __syncthreads();   // weight + slab0 staged (vmcnt(0) drain)

    #pragma unroll
    for (int ck = 0; ck < 8; ++ck) {     // K-steps of 16
        const int buf = ck & 1;
        if (ck < 7) STAGE_SLAB(ck + 1, buf ^ 1);

        // B-frag from slab: two b128 at [2kg][rloc][.] and [2kg+1][rloc][.]
        const char* sb = (const char*)islab + buf * 16384;
        f32x4 v0 = *(const f32x4*)(sb + (2 * kg) * 4096 + rloc * 16);
        f32x4 v1 = *(const f32x4*)(sb + (2 * kg + 1) * 4096 + rloc * 16);
        bf16x8 bfrag;
        #pragma unroll
        for (int e = 0; e < 4; ++e) {
            bfrag[e]     = (__bf16)v0[e];
            bfrag[e + 4] = (__bf16)v1[e];
        }

        const int c0 = ck * 16 + kg * 8;
        #pragma unroll
        for (int mt = 0; mt < 4; ++mt) { // 4 f subtiles of 32
            const int f = mt * 32 + nl;
            bf16x8 af = *(const bf16x8*)&wt[f * CAT_ + (c0 ^ ((f & 7) << 3))];
            acc[mt] = __builtin_amdgcn_mfma_f32_32x32x16_bf16(af, bfrag, acc[mt], 0, 0, 0);
        }

        __syncthreads();  // drains staging (vmcnt) + frag reads (lgkm)
    }

    // epilogue: D col=lane&31 -> n, row=(reg&3)+8*(reg>>2)+4*kg -> f
    // (m74/m101 verified); full-128B-line stores
    float* outp = out + (size_t)b * FEAT_ * N_ + nbase + wid * 32 + nl;
    #pragma unroll
    for (int mt = 0; mt < 4; ++mt) {
        #pragma unroll
        for (int r = 0; r < 16; ++r) {
            const int f = mt * 32 + (r & 3) + 8 * (r >> 2) + 4 * kg;
            __builtin_nontemporal_store(acc[mt][r], outp + (size_t)f * N_);
        }
    }
    #undef STAGE_SLAB
}

// ---------------------------------------------------------------------------
// Fallback (R1 kernel): single launch with per-block LDS staging, used only
// if the workspace is too small for wT_swz.
// ---------------------------------------------------------------------------
constexpr int LDSTR = 136;
constexpr int FB_BLOCKS = (B_ * N_) / 128;  // 2048

__global__ __launch_bounds__(256, 4) void ocm_fused(
    const float* __restrict__ input,
    const float* __restrict__ weight,
    const int* __restrict__ keys,
    const float* __restrict__ values,
    float* __restrict__ out)
{
    const int bid = blockIdx.x;
    const int tid = threadIdx.x;

    if (bid >= FB_BLOCKS) {
        float* outw = out + (size_t)B_ * FEAT_ * N_;
        const int r = bid - FB_BLOCKS;
        bool keyed = false;
        for (int i = 0; i < K_; ++i) keyed |= (keys[i] == r);
        if (!keyed && tid < FEAT_)
            outw[r * FEAT_ + tid] = weight[r * FEAT_ + tid];
        if (r < K_ && tid < 64) {
            const int key = keys[r];
            float a0 = DELTA_ * weight[key * FEAT_ + tid]      + (1.0f - DELTA_) * values[r * FEAT_ + tid];
            float a1 = DELTA_ * weight[key * FEAT_ + tid + 64] + (1.0f - DELTA_) * values[r * FEAT_ + tid + 64];
            float ss = a0 * a0 + a1 * a1;
            #pragma unroll
            for (int off = 32; off > 0; off >>= 1)
                ss += __shfl_down(ss, off, 64);
            float nrm = sqrtf(__shfl(ss, 0, 64));
            outw[key * FEAT_ + tid]      = nrm;
            outw[key * FEAT_ + tid + 64] = nrm;
        }
        return;
    }

    __shared__ __bf16 wt[FEAT_ * LDSTR];
    #pragma unroll
    for (int j = 0; j < (CAT_ * FEAT_) / 256; ++j) {
        int i = tid + j * 256;
        int c = i >> 7;
        int f = i & (FEAT_ - 1);
        wt[f * LDSTR + c] = (__bf16)weight[i];
    }
    __syncthreads();

    const int wid  = tid >> 6;
    const int lane = tid & 63;
    const int qlo  = lane & 15;
    const int qhi  = lane >> 4;
    const int b    = bid >> 8;
    const int nb   = bid & 255;
    const int n0   = nb * 128 + wid * 32;

    f32x4 acc[8][2];
    #pragma unroll
    for (int i = 0; i < 8; ++i)
        #pragma unroll
        for (int j = 0; j < 2; ++j)
            acc[i][j] = (f32x4)0.0f;

    const float* in_base = input + ((size_t)b * N_ + n0) * CAT_;

    #pragma unroll
    for (int ck = 0; ck < 4; ++ck) {
        bf16x8 bfrag[2];
        #pragma unroll
        for (int nt = 0; nt < 2; ++nt) {
            const float* p = in_base + (size_t)(nt * 16 + qlo) * CAT_ + ck * 32 + qhi * 8;
            f32x4 v0 = *(const f32x4*)p;
            f32x4 v1 = *(const f32x4*)(p + 4);
            bf16x8 t;
            t[0] = (__bf16)v0[0]; t[1] = (__bf16)v0[1]; t[2] = (__bf16)v0[2]; t[3] = (__bf16)v0[3];
            t[4] = (__bf16)v1[0]; t[5] = (__bf16)v1[1]; t[6] = (__bf16)v1[2]; t[7] = (__bf16)v1[3];
            bfrag[nt] = t;
        }
        #pragma unroll
        for (int mt = 0; mt < 8; ++mt) {
            bf16x8 afrag = *(const bf16x8*)&wt[(mt * 16 + qlo) * LDSTR + ck * 32 + qhi * 8];
            acc[mt][0] = __builtin_amdgcn_mfma_f32_16x16x32_bf16(afrag, bfrag[0], acc[mt][0], 0, 0, 0);
            acc[mt][1] = __builtin_amdgcn_mfma_f32_16x16x32_bf16(afrag, bfrag[1], acc[mt][1], 0, 0, 0);
        }
    }

    float* outp = out + (size_t)b * FEAT_ * N_ + n0;
    #pragma unroll
    for (int mt = 0; mt < 8; ++mt) {
        #pragma unroll
        for (int nt = 0; nt < 2; ++nt) {
            #pragma unroll
            for (int r = 0; r < 4; ++r) {
                int f = mt * 16 + qhi * 4 + r;
                outp[(size_t)f * N_ + nt * 16 + qlo] = acc[mt][nt][r];
            }
        }
    }
}

extern "C" void kernel_launch(void* const* d_in, const int* in_sizes, int n_in,
                              void* d_out, int out_size, void* d_ws, size_t ws_size,
                              hipStream_t stream) {
    const float* input  = (const float*)d_in[0];
    const float* weight = (const float*)d_in[1];
    const int*   keys   = (const int*)d_in[2];
    const float* values = (const float*)d_in[3];
    float* out = (float*)d_out;

    if (ws_size >= (size_t)CAT_ * FEAT_ * sizeof(__bf16)) {
        __bf16* wTs = (__bf16*)d_ws;
        float* outw = out + (size_t)B_ * FEAT_ * N_;
        prep_kernel<<<CAT_, FEAT_, 0, stream>>>(weight, keys, values, outw, wTs);
        gemm_kernel<<<GEMM_BLOCKS, BLOCK, 0, stream>>>(input, wTs, out);
    } else {
        ocm_fused<<<FB_BLOCKS + CAT_, 256, 0, stream>>>(input, weight, keys, values, out);
    }
}